// Round 2
// baseline (679.392 us; speedup 1.0000x reference)
//
#include <hip/hip_runtime.h>
#include <hip/hip_bf16.h>

#define S 2048
#define D 128
#define NH 16
#define TM 128
#define TN 128
#define BK 64
#define LROW (BK + 8)   // bf16 elems per LDS row: 144 B stride breaks pow2 bank stride

typedef __bf16 bf16x8 __attribute__((ext_vector_type(8)));
typedef __bf16 bf16x4 __attribute__((ext_vector_type(4)));
typedef float  f32x4  __attribute__((ext_vector_type(4)));

__global__ __launch_bounds__(256, 2)
void alibi_scores(const float* __restrict__ q,
                  const float* __restrict__ k,
                  const float* __restrict__ head_scales,
                  const float* __restrict__ slopes,
                  const float* __restrict__ positions,
                  const int* __restrict__ tok,
                  float* __restrict__ out)
{
    __shared__ __align__(16) __bf16 As[TM * LROW];
    __shared__ __align__(16) __bf16 Bs[TN * LROW];
    __shared__ float posQ[TM];
    __shared__ float posK[TN];

    const int tid = threadIdx.x;
    const int bh  = blockIdx.z;
    const int b   = bh >> 4;          // / NH
    const int h   = bh & 15;          // % NH
    const int tm  = blockIdx.y * TM;
    const int tn  = blockIdx.x * TN;

    // gather ALiBi positions for this tile's rows and cols (exact fp32)
    if (tid < TM)
        posQ[tid] = positions[tok[b * S + tm + tid]];
    else
        posK[tid - TM] = positions[tok[b * S + tn + (tid - TM)]];

    const float* qb = q + (size_t)bh * S * D;
    const float* kb = k + (size_t)bh * S * D;

    const int lane = tid & 63;
    const int wv   = tid >> 6;
    const int wm   = (wv >> 1) * 64;  // wave's 64x64 quadrant
    const int wn   = (wv & 1) * 64;
    const int col  = lane & 15;
    const int quad = lane >> 4;

    f32x4 acc[4][4];
    #pragma unroll
    for (int i = 0; i < 4; ++i)
        #pragma unroll
        for (int j = 0; j < 4; ++j)
            acc[i][j] = (f32x4){0.f, 0.f, 0.f, 0.f};

    #pragma unroll
    for (int kc = 0; kc < D; kc += BK) {
        // stage chunk: 128 rows x 64 fp32 -> bf16 LDS. Flat float4 mapping:
        // g = it*256+tid, row = g/16, col4 = (g%16)*4 -> wave reads 4 contiguous
        // 256B row-chunks per iteration (coalesced dwordx4).
        #pragma unroll
        for (int it = 0; it < 8; ++it) {
            const int g = it * 256 + tid;
            const int r = g >> 4;
            const int c = (g & 15) * 4;
            f32x4 va = *reinterpret_cast<const f32x4*>(qb + (size_t)(tm + r) * D + kc + c);
            f32x4 vb = *reinterpret_cast<const f32x4*>(kb + (size_t)(tn + r) * D + kc + c);
            bf16x4 a4, b4;
            #pragma unroll
            for (int j = 0; j < 4; ++j) { a4[j] = (__bf16)va[j]; b4[j] = (__bf16)vb[j]; }
            *reinterpret_cast<bf16x4*>(&As[r * LROW + c]) = a4;
            *reinterpret_cast<bf16x4*>(&Bs[r * LROW + c]) = b4;
        }
        __syncthreads();

        #pragma unroll
        for (int ks = 0; ks < BK; ks += 32) {
            const int kf = ks + quad * 8;
            bf16x8 af[4], bfr[4];
            #pragma unroll
            for (int mi = 0; mi < 4; ++mi)
                af[mi] = *reinterpret_cast<const bf16x8*>(&As[(wm + mi * 16 + col) * LROW + kf]);
            #pragma unroll
            for (int ni = 0; ni < 4; ++ni)
                bfr[ni] = *reinterpret_cast<const bf16x8*>(&Bs[(wn + ni * 16 + col) * LROW + kf]);
            #pragma unroll
            for (int mi = 0; mi < 4; ++mi)
                #pragma unroll
                for (int ni = 0; ni < 4; ++ni)
                    acc[mi][ni] = __builtin_amdgcn_mfma_f32_16x16x32_bf16(
                        af[mi], bfr[ni], acc[mi][ni], 0, 0, 0);
        }
        __syncthreads();
    }

    // epilogue: scale + ALiBi bias in fp32, store fp32
    const float scale = head_scales[h] * 0.08838834764831845f; // 1/sqrt(128)
    const float slope = slopes[h];
    float* ob = out + (size_t)bh * S * S;

    #pragma unroll
    for (int mi = 0; mi < 4; ++mi) {
        const int r0 = wm + mi * 16 + quad * 4;
        #pragma unroll
        for (int ni = 0; ni < 4; ++ni) {
            const int c = wn + ni * 16 + col;
            const float pk = posK[c];
            float* op = ob + (size_t)(tm + r0) * S + tn + c;
            #pragma unroll
            for (int r = 0; r < 4; ++r) {
                float v = acc[mi][ni][r] * scale - slope * (posQ[r0 + r] - pk);
                op[(size_t)r * S] = v;
            }
        }
    }
}

extern "C" void kernel_launch(void* const* d_in, const int* in_sizes, int n_in,
                              void* d_out, int out_size, void* d_ws, size_t ws_size,
                              hipStream_t stream)
{
    (void)in_sizes; (void)n_in; (void)d_ws; (void)ws_size; (void)out_size;
    const float* q  = (const float*)d_in[0];
    const float* k  = (const float*)d_in[1];
    const float* hs = (const float*)d_in[2];
    const float* sl = (const float*)d_in[3];
    const float* ps = (const float*)d_in[4];
    const int*   ti = (const int*)d_in[5];
    float* out      = (float*)d_out;

    dim3 grid(S / TN, S / TM, 2 * NH);  // x=col tile, y=row tile, z=batch*head
    alibi_scores<<<grid, 256, 0, stream>>>(q, k, hs, sl, ps, ti, out);
}